// Round 1
// baseline (2713.206 us; speedup 1.0000x reference)
//
#include <hip/hip_runtime.h>

#define DD 128
#define BSZ 128
#define SEQL 128
#define TST 127
#define QNN 4
#define CNN 10
#define NQCC 4
#define RKK 10
#define NEGV -1000000000.0f

// ---- workspace float offsets ----
#define OFF_WTHH1   0         // [128][384]  W_hh1^T
#define OFF_WTIH2   49152     // [128][384]  W_ih2^T
#define OFF_WTHH2   98304     // [128][384]  W_hh2^T
#define OFF_WQT     147456    // [128][128]  Wq^T
#define OFF_WKT     163840    // [128][128]  Wk^T
#define OFF_WTA0    180224    // [128][128]  W_agg0^T
#define OFF_WTA1    196608    // [128][128]  W_agg1^T
#define OFF_WTAL    212992    // [128][128]  W_agg_last^T
#define OFF_WTIH1A  229376    // [128][384]  W_ih1[:, :128]^T
#define OFF_ERIH1   278528    // [2][384]    W_ih1[:,128:]@Er[r]
#define OFF_ECA0    279296    // [1000][128] W_agg0 @ Ec[c]
#define OFF_E1C     407296    // [1000][128] tanh(W_agg1@(cmean+Ec)+b1)
#define OFF_GI1     535296    // [16256][384]
#define OFF_TIX     6777600   // [16256][10] int
#define OFF_TMSK    6940160   // [16256][10] int
#define OFF_QPH     7102720   // [128][128][128] per-b cached Qp of state_hist

__device__ __forceinline__ float sigm(float x) { return 1.0f / (1.0f + __expf(-x)); }

// ---------------- K0a: weight transposes & small precomputes ----------------
__global__ __launch_bounds__(256) void k_prep(
    const float* __restrict__ W_hh1, const float* __restrict__ W_ih2,
    const float* __restrict__ W_hh2, const float* __restrict__ Wq,
    const float* __restrict__ Wk, const float* __restrict__ W_agg,
    const float* __restrict__ W_agg_last, const float* __restrict__ W_ih1,
    const float* __restrict__ Er, float* __restrict__ ws) {
  int idx = blockIdx.x * 256 + threadIdx.x;
  const int total = 279296;
  for (int o = idx; o < total; o += gridDim.x * 256) {
    int r = o;
    if (r < 49152) { int j = r / 384, i = r % 384; ws[OFF_WTHH1 + r] = W_hh1[i * 128 + j]; continue; }
    r -= 49152;
    if (r < 49152) { int j = r / 384, i = r % 384; ws[OFF_WTIH2 + r] = W_ih2[i * 128 + j]; continue; }
    r -= 49152;
    if (r < 49152) { int j = r / 384, i = r % 384; ws[OFF_WTHH2 + r] = W_hh2[i * 128 + j]; continue; }
    r -= 49152;
    if (r < 16384) { int j = r / 128, i = r % 128; ws[OFF_WQT + r] = Wq[i * 128 + j]; continue; }
    r -= 16384;
    if (r < 16384) { int j = r / 128, i = r % 128; ws[OFF_WKT + r] = Wk[i * 128 + j]; continue; }
    r -= 16384;
    if (r < 16384) { int j = r / 128, i = r % 128; ws[OFF_WTA0 + r] = W_agg[i * 128 + j]; continue; }
    r -= 16384;
    if (r < 16384) { int j = r / 128, i = r % 128; ws[OFF_WTA1 + r] = W_agg[16384 + i * 128 + j]; continue; }
    r -= 16384;
    if (r < 16384) { int j = r / 128, i = r % 128; ws[OFF_WTAL + r] = W_agg_last[i * 128 + j]; continue; }
    r -= 16384;
    if (r < 49152) { int j = r / 384, i = r % 384; ws[OFF_WTIH1A + r] = W_ih1[i * 256 + j]; continue; }
    r -= 49152;
    { // ErIH1[rr][i] = sum_j Er[rr][j] * W_ih1[i][128+j]
      int rr = r / 384, i2 = r % 384;
      float a = 0.f;
      for (int j = 0; j < 128; ++j) a += Er[rr * 128 + j] * W_ih1[i2 * 256 + 128 + j];
      ws[OFF_ERIH1 + r] = a;
    }
  }
}

// ---------------- K0b: per-concept tables ----------------
__global__ __launch_bounds__(128) void k_concept(
    const int* __restrict__ cnbr, const float* __restrict__ Eq,
    const float* __restrict__ Ec, const float* __restrict__ b_agg,
    float* __restrict__ ws) {
  int c = blockIdx.x;
  int tid = threadIdx.x;
  __shared__ int s_nb[CNN];
  __shared__ float s_v[DD], s_ec[DD];
  if (tid < CNN) s_nb[tid] = cnbr[c * CNN + tid];
  __syncthreads();
  float ec = Ec[c * DD + tid];
  float cm = 0.f;
#pragma unroll
  for (int l = 0; l < CNN; ++l) cm += Eq[s_nb[l] * DD + tid];
  s_ec[tid] = ec;
  s_v[tid] = cm * 0.1f + ec;
  __syncthreads();
  const float* WtA0 = ws + OFF_WTA0;
  const float* WtA1 = ws + OFF_WTA1;
  float a1 = 0.f, a0 = 0.f;
#pragma unroll 8
  for (int j = 0; j < DD; ++j) {
    a1 += WtA1[j * DD + tid] * s_v[j];
    a0 += WtA0[j * DD + tid] * s_ec[j];
  }
  ws[OFF_E1C + c * DD + tid] = tanhf(a1 + b_agg[DD + tid]);
  ws[OFF_ECA0 + c * DD + tid] = a0;
}

// ---------------- K0c: per-(b,t) aggregation + gi1 ----------------
__global__ __launch_bounds__(128) void k_agg(
    const int* __restrict__ qseq, const int* __restrict__ rseq,
    const int* __restrict__ mseq, const int* __restrict__ qnbr,
    const float* __restrict__ Eq, const float* __restrict__ b_agg,
    const float* __restrict__ b_agg_last, const float* __restrict__ b_ih1,
    float* __restrict__ ws) {
  int bt = blockIdx.x;
  int b = bt / TST, t = bt - b * TST;
  int tid = threadIdx.x;
  __shared__ int s_n1[QNN];
  __shared__ int s_qrm[3];
  __shared__ float s_a[DD], s_b[DD], s_c[DD];
  if (tid < 3) s_qrm[tid] = (tid == 0) ? qseq[b * SEQL + t] : (tid == 1 ? rseq[b * SEQL + t] : mseq[b * SEQL + t]);
  __syncthreads();
  int q = s_qrm[0];
  if (tid < QNN) s_n1[tid] = qnbr[q * QNN + tid];
  s_a[tid] = Eq[q * DD + tid];
  __syncthreads();
  const float* WtA0 = ws + OFF_WTA0;
  const float* WtAL = ws + OFF_WTAL;
  const float* WtIH1A = ws + OFF_WTIH1A;
  const float* EcA0 = ws + OFF_ECA0;
  const float* E1C = ws + OFF_E1C;
  float a = 0.f;
#pragma unroll 8
  for (int j = 0; j < DD; ++j) a += WtA0[j * DD + tid] * s_a[j];
  int n0 = s_n1[0], n1 = s_n1[1], n2 = s_n1[2], n3 = s_n1[3];
  float pre0 = 0.25f * (EcA0[n0 * DD + tid] + EcA0[n1 * DD + tid] + EcA0[n2 * DD + tid] + EcA0[n3 * DD + tid]);
  float e0 = tanhf(a + pre0 + b_agg[tid]);
  float e1m = 0.25f * (E1C[n0 * DD + tid] + E1C[n1 * DD + tid] + E1C[n2 * DD + tid] + E1C[n3 * DD + tid]);
  s_b[tid] = e1m + e0;  // u
  __syncthreads();
  a = 0.f;
#pragma unroll 8
  for (int j = 0; j < DD; ++j) a += WtA0[j * DD + tid] * s_b[j];
  s_c[tid] = tanhf(a + b_agg[tid]);  // e0b
  __syncthreads();
  a = 0.f;
#pragma unroll 8
  for (int j = 0; j < DD; ++j) a += WtAL[j * DD + tid] * s_c[j];
  float aggv = tanhf(a + b_agg_last[tid]);
  __syncthreads();
  s_b[tid] = s_qrm[2] ? aggv : s_a[tid];  // emb_q
  __syncthreads();
  const float* ErI = ws + OFF_ERIH1 + s_qrm[1] * 384;
  float g0 = 0.f, g1 = 0.f, g2a = 0.f;
#pragma unroll 4
  for (int j = 0; j < DD; ++j) {
    float x = s_b[j];
    g0 += WtIH1A[j * 384 + tid] * x;
    g1 += WtIH1A[j * 384 + 128 + tid] * x;
    g2a += WtIH1A[j * 384 + 256 + tid] * x;
  }
  float* gi1 = ws + OFF_GI1 + (size_t)bt * 384;
  gi1[tid] = g0 + ErI[tid] + b_ih1[tid];
  gi1[128 + tid] = g1 + ErI[128 + tid] + b_ih1[128 + tid];
  gi1[256 + tid] = g2a + ErI[256 + tid] + b_ih1[256 + tid];
}

// ---------------- K2: per-(b,t) scores + top-10 (JAX tie-break: lower idx) ----------------
__global__ __launch_bounds__(128) void k_topk(
    const int* __restrict__ qseq, const float* __restrict__ Eq,
    float* __restrict__ ws) {
  int* tix = (int*)(ws + OFF_TIX);
  int* tmsk = (int*)(ws + OFF_TMSK);
  int bt = blockIdx.x;
  int b = bt / TST, t = bt - b * TST;
  int tid = threadIdx.x;
  int lane = tid & 63, wv = tid >> 6;
  __shared__ float s_e[DD];
  __shared__ float s_sc[SEQL];
  __shared__ float s_wv[2];
  __shared__ int s_wi[2];
  int qn = qseq[b * SEQL + t + 1];
  s_e[tid] = Eq[qn * DD + tid];
  __syncthreads();
  float sc = NEGV;
  if (tid < t) {
    int qs = qseq[b * SEQL + tid];
    float a = 0.f;
#pragma unroll 8
    for (int j = 0; j < DD; ++j) a += Eq[qs * DD + j] * s_e[j];
    sc = a;
  }
  s_sc[tid] = sc;
  __syncthreads();
  for (int k = 0; k < RKK; ++k) {
    float v = s_sc[tid];
    int ix = tid;
    for (int off = 32; off > 0; off >>= 1) {
      float ov = __shfl_down(v, off);
      int oi = __shfl_down(ix, off);
      if (ov > v || (ov == v && oi < ix)) { v = ov; ix = oi; }
    }
    if (lane == 0) { s_wv[wv] = v; s_wi[wv] = ix; }
    __syncthreads();
    if (tid == 0) {
      float v0 = s_wv[0], v1 = s_wv[1];
      int i0 = s_wi[0], i1 = s_wi[1];
      if (v1 > v0 || (v1 == v0 && i1 < i0)) { v0 = v1; i0 = i1; }
      tix[bt * RKK + k] = i0;
      tmsk[bt * RKK + k] = (v0 > NEGV * 0.5f) ? 1 : 0;
      s_sc[i0] = -__builtin_inff();
    }
    __syncthreads();
  }
}

// ---------------- K3: sequential scan, 1 block per batch row ----------------
__global__ __launch_bounds__(256) void k_seq(
    const int* __restrict__ qseq, const int* __restrict__ qctab,
    const float* __restrict__ Eq, const float* __restrict__ Ec,
    const float* __restrict__ b_hh1, const float* __restrict__ b_ih2,
    const float* __restrict__ b_hh2, const float* __restrict__ bq,
    const float* __restrict__ bk, const float* __restrict__ Ww,
    const float* __restrict__ bw, const float* __restrict__ h1i,
    const float* __restrict__ h2i, float* __restrict__ ws,
    float* __restrict__ out) {
  const float* WtHH1 = ws + OFF_WTHH1;
  const float* WtIH2 = ws + OFF_WTIH2;
  const float* WtHH2 = ws + OFF_WTHH2;
  const float* WqT = ws + OFF_WQT;
  const float* WkT = ws + OFF_WKT;
  const float* gi1_all = ws + OFF_GI1;
  const int* tix_all = (const int*)(ws + OFF_TIX);
  const int* tmsk_all = (const int*)(ws + OFF_TMSK);
  int b = blockIdx.x;
  int tid = threadIdx.x;
  int lane = tid & 63, wv = tid >> 6;
  float* qph = ws + OFF_QPH + (size_t)b * SEQL * DD;  // cached Qp of state_hist rows

  __shared__ float s_h1[DD], s_h2[DD], s_h1n[DD], s_g2[DD], s_Qpg2[DD];
  __shared__ float s_gh1[384], s_gi2[384], s_gh2[384];
  __shared__ float s_vhh[SEQL];
  __shared__ float s_qc[5][DD], s_Kp[5][DD];
  __shared__ float s_hQp[11][DD];
  __shared__ float s_vh[11], s_vqc[5];
  __shared__ int s_hm[11], s_tix[RKK], s_cid[5];
  __shared__ float s_logit[64];

  // init: Qp(zero state)=bq, vh(zero state)=0
  for (int o = tid; o < SEQL * DD; o += 256) qph[o] = bq[o & 127];
  if (tid < DD) { s_h1[tid] = h1i[b * DD + tid]; s_h2[tid] = h2i[b * DD + tid]; }
  if (tid < SEQL) s_vhh[tid] = 0.f;
  if (tid == 0) out[b * SEQL + 1] = 0.f;  // never written by any step
  __syncthreads();

  for (int t = 0; t < TST; ++t) {
    // -- phase 1: gh1 = b_hh1 + W_hh1 @ h1
    if (tid < 128) {
      float a0 = 0.f, a1 = 0.f;
#pragma unroll 8
      for (int j = 0; j < DD; ++j) {
        float x = s_h1[j];
        a0 += WtHH1[j * 384 + tid] * x;
        a1 += WtHH1[j * 384 + 256 + tid] * x;
      }
      s_gh1[tid] = a0 + b_hh1[tid];
      s_gh1[256 + tid] = a1 + b_hh1[256 + tid];
    } else {
      float a0 = 0.f;
#pragma unroll 8
      for (int j = 0; j < DD; ++j) a0 += WtHH1[j * 384 + tid] * s_h1[j];
      s_gh1[tid] = a0 + b_hh1[tid];
    }
    __syncthreads();
    // -- phase 2: GRU1 combine
    if (tid < DD) {
      const float* gi = gi1_all + (size_t)(b * TST + t) * 384;
      float r = sigm(gi[tid] + s_gh1[tid]);
      float z = sigm(gi[128 + tid] + s_gh1[128 + tid]);
      float n = tanhf(gi[256 + tid] + r * s_gh1[256 + tid]);
      s_h1n[tid] = (1.f - z) * n + z * s_h1[tid];
    }
    __syncthreads();
    // -- phase 3: gi2 = W_ih2 @ h1n ; gh2 = W_hh2 @ h2
    if (tid < 128) {
      float a0 = 0.f, a1 = 0.f, c0 = 0.f, c1 = 0.f;
#pragma unroll 4
      for (int j = 0; j < DD; ++j) {
        float xn = s_h1n[j], xh = s_h2[j];
        a0 += WtIH2[j * 384 + tid] * xn;
        a1 += WtIH2[j * 384 + 256 + tid] * xn;
        c0 += WtHH2[j * 384 + tid] * xh;
        c1 += WtHH2[j * 384 + 256 + tid] * xh;
      }
      s_gi2[tid] = a0 + b_ih2[tid];
      s_gi2[256 + tid] = a1 + b_ih2[256 + tid];
      s_gh2[tid] = c0 + b_hh2[tid];
      s_gh2[256 + tid] = c1 + b_hh2[256 + tid];
    } else {
      float a0 = 0.f, c0 = 0.f;
#pragma unroll 8
      for (int j = 0; j < DD; ++j) {
        a0 += WtIH2[j * 384 + tid] * s_h1n[j];
        c0 += WtHH2[j * 384 + tid] * s_h2[j];
      }
      s_gi2[tid] = a0 + b_ih2[tid];
      s_gh2[tid] = c0 + b_hh2[tid];
    }
    __syncthreads();
    // -- phase 4: GRU2 combine -> g2 ; load qc ids
    if (tid < DD) {
      float r = sigm(s_gi2[tid] + s_gh2[tid]);
      float z = sigm(s_gi2[128 + tid] + s_gh2[128 + tid]);
      float n = tanhf(s_gi2[256 + tid] + r * s_gh2[256 + tid]);
      s_g2[tid] = (1.f - z) * n + z * s_h2[tid];
    }
    if (tid >= 128 && tid < 133) {
      int qn = qseq[b * SEQL + t + 1];
      s_cid[tid - 128] = (tid == 128) ? qn : qctab[qn * NQCC + (tid - 129)];
    }
    __syncthreads();
    // -- phase 5a: load qc rows
    for (int o = tid; o < 5 * DD; o += 256) {
      int s = o >> 7, i = o & 127;
      s_qc[s][i] = (s == 0) ? Eq[s_cid[0] * DD + i] : Ec[s_cid[s] * DD + i];
    }
    __syncthreads();
    // -- phase 5b: waves0-1: Qp(g2) & Kp ; waves2-3: scalar dots + idx loads
    if (tid < 128) {
      float aq = 0.f, k0 = 0.f, k1 = 0.f, k2 = 0.f, k3 = 0.f, k4 = 0.f;
#pragma unroll 4
      for (int j = 0; j < DD; ++j) {
        float wq = WqT[j * DD + tid], wk = WkT[j * DD + tid];
        aq += wq * s_g2[j];
        k0 += wk * s_qc[0][j];
        k1 += wk * s_qc[1][j];
        k2 += wk * s_qc[2][j];
        k3 += wk * s_qc[3][j];
        k4 += wk * s_qc[4][j];
      }
      s_Qpg2[tid] = aq + bq[tid];
      float bkt = bk[tid];
      s_Kp[0][tid] = k0 + bkt;
      s_Kp[1][tid] = k1 + bkt;
      s_Kp[2][tid] = k2 + bkt;
      s_Kp[3][tid] = k3 + bkt;
      s_Kp[4][tid] = k4 + bkt;
    } else {
      int w2 = wv - 2;
      for (int dd2 = w2; dd2 < 6; dd2 += 2) {
        float pa;
        if (dd2 == 0)
          pa = s_g2[lane] * Ww[lane] + s_g2[lane + 64] * Ww[lane + 64];
        else {
          int s = dd2 - 1;
          pa = s_qc[s][lane] * Ww[128 + lane] + s_qc[s][lane + 64] * Ww[128 + lane + 64];
        }
        for (int off = 32; off > 0; off >>= 1) pa += __shfl_down(pa, off);
        if (lane == 0) {
          if (dd2 == 0) s_vh[0] = pa;
          else s_vqc[dd2 - 1] = pa;
        }
      }
      if (tid >= 192 && tid < 202) s_tix[tid - 192] = tix_all[(b * TST + t) * RKK + tid - 192];
      if (tid >= 202 && tid < 212) s_hm[1 + tid - 202] = tmsk_all[(b * TST + t) * RKK + tid - 202];
      if (tid == 212) s_hm[0] = 1;
    }
    __syncthreads();
    // -- phase 6: stage hist Qp rows & vh
    for (int o = tid; o < 11 * DD; o += 256) {
      int q = o >> 7, i = o & 127;
      s_hQp[q][i] = (q == 0) ? s_Qpg2[i] : qph[s_tix[q - 1] * DD + i];
    }
    if (tid >= 1 && tid < 11) s_vh[tid] = s_vhh[s_tix[tid - 1]];
    __syncthreads();
    // -- phase 7: logits (55 dots, 4 lanes each)
    if (tid < 220) {
      int p = tid >> 2, sub = tid & 3;
      int q = p / 5, s = p - q * 5;
      float a = 0.f;
      int j0 = sub * 32;
#pragma unroll 8
      for (int j = j0; j < j0 + 32; ++j) a += s_hQp[q][j] * s_Kp[s][j];
      a += __shfl_down(a, 1);
      a += __shfl_down(a, 2);
      if (sub == 0) s_logit[p] = s_hm[q] ? a : NEGV;
    }
    if (tid < 9) s_logit[55 + tid] = NEGV;
    __syncthreads();
    // -- phase 8: softmax over 55 + weighted sigmoid sum -> output
    if (tid < 64) {
      float l = s_logit[tid];
      float m = l;
      for (int off = 32; off > 0; off >>= 1) m = fmaxf(m, __shfl_xor(m, off));
      float e = __expf(l - m);
      float v = 0.f;
      if (tid < 55) {
        int q = tid / 5, s = tid - q * 5;
        v = sigm(s_vh[q] + s_vqc[s] + bw[0]);
      }
      float num = e * v, den = e;
      for (int off = 32; off > 0; off >>= 1) {
        num += __shfl_xor(num, off);
        den += __shfl_xor(den, off);
      }
      if (tid == 0) out[b * SEQL + ((t == 0) ? 0 : (t + 1))] = num / den;
    }
    __syncthreads();
    // -- phase 9: commit
    if (tid < DD) {
      s_h1[tid] = s_h1n[tid];
      if (t > 0) {
        s_h2[tid] = s_g2[tid];
        qph[t * DD + tid] = s_Qpg2[tid];
      }
    }
    if (tid == 0 && t > 0) s_vhh[t] = s_vh[0];
    __syncthreads();
  }
}

extern "C" void kernel_launch(void* const* d_in, const int* in_sizes, int n_in,
                              void* d_out, int out_size, void* d_ws, size_t ws_size,
                              hipStream_t stream) {
  const int* qseq = (const int*)d_in[0];
  const int* rseq = (const int*)d_in[1];
  const int* mseq = (const int*)d_in[2];
  const int* qnbr = (const int*)d_in[3];
  const int* cnbr = (const int*)d_in[4];
  const int* qctab = (const int*)d_in[5];
  const float* Eq = (const float*)d_in[6];
  const float* Ec = (const float*)d_in[7];
  const float* Er = (const float*)d_in[8];
  const float* W_ih1 = (const float*)d_in[9];
  const float* W_hh1 = (const float*)d_in[10];
  const float* b_ih1 = (const float*)d_in[11];
  const float* b_hh1 = (const float*)d_in[12];
  const float* W_ih2 = (const float*)d_in[13];
  const float* W_hh2 = (const float*)d_in[14];
  const float* b_ih2 = (const float*)d_in[15];
  const float* b_hh2 = (const float*)d_in[16];
  const float* W_agg = (const float*)d_in[17];
  const float* b_agg = (const float*)d_in[18];
  const float* W_agg_last = (const float*)d_in[19];
  const float* b_agg_last = (const float*)d_in[20];
  const float* Wq = (const float*)d_in[21];
  const float* bq = (const float*)d_in[22];
  const float* Wk = (const float*)d_in[23];
  const float* bk = (const float*)d_in[24];
  const float* Ww = (const float*)d_in[25];
  const float* bw = (const float*)d_in[26];
  const float* h1i = (const float*)d_in[27];
  const float* h2i = (const float*)d_in[28];
  float* ws = (float*)d_ws;
  float* out = (float*)d_out;

  hipLaunchKernelGGL(k_prep, dim3(1091), dim3(256), 0, stream,
                     W_hh1, W_ih2, W_hh2, Wq, Wk, W_agg, W_agg_last, W_ih1, Er, ws);
  hipLaunchKernelGGL(k_concept, dim3(1000), dim3(128), 0, stream,
                     cnbr, Eq, Ec, b_agg, ws);
  hipLaunchKernelGGL(k_agg, dim3(BSZ * TST), dim3(128), 0, stream,
                     qseq, rseq, mseq, qnbr, Eq, b_agg, b_agg_last, b_ih1, ws);
  hipLaunchKernelGGL(k_topk, dim3(BSZ * TST), dim3(128), 0, stream,
                     qseq, Eq, ws);
  hipLaunchKernelGGL(k_seq, dim3(BSZ), dim3(256), 0, stream,
                     qseq, qctab, Eq, Ec, b_hh1, b_ih2, b_hh2, bq, bk, Ww, bw,
                     h1i, h2i, ws, out);
}